// Round 1
// baseline (702.584 us; speedup 1.0000x reference)
//
#include <hip/hip_runtime.h>
#include <hip/hip_bf16.h>
#include <math.h>

// Problem constants (from reference)
#define PTOK 4096      // P
#define BDIM 4         // B
#define FULLD 4096     // FULL
#define SLICE 512
#define SL_START 1024
#define EDIM 1024
#define GDIM 128       // SLICE/4
#define FP_MIN_C 0.1875f
#define FP_MAX_C 0.4375f

// ---------------------------------------------------------------------------
// 1) mask + prefix-scan compaction of fingerprints -> idx[N]
// ---------------------------------------------------------------------------
__global__ __launch_bounds__(1024) void scan_kernel(const float* __restrict__ fp,
                                                    int* __restrict__ idx) {
    __shared__ int cnt[1024];
    int t = threadIdx.x;
    int m[4];
    int c = 0;
#pragma unroll
    for (int i = 0; i < 4; ++i) {
        float f = fp[t * 4 + i];
        m[i] = (f >= FP_MIN_C && f < FP_MAX_C) ? 1 : 0;
        c += m[i];
    }
    cnt[t] = c;
    __syncthreads();
    // Hillis-Steele inclusive scan over 1024 entries
    for (int off = 1; off < 1024; off <<= 1) {
        int add = (t >= off) ? cnt[t - off] : 0;
        __syncthreads();
        cnt[t] += add;
        __syncthreads();
    }
    int pos = cnt[t] - c;  // exclusive prefix
#pragma unroll
    for (int i = 0; i < 4; ++i) {
        if (m[i]) idx[pos++] = t * 4 + i;
    }
}

// ---------------------------------------------------------------------------
// 2) normalize pentachoron -> dirs (5 x 1024)
// ---------------------------------------------------------------------------
__global__ __launch_bounds__(256) void dirs_kernel(const float* __restrict__ penta,
                                                   float* __restrict__ dirs) {
    int v = blockIdx.x, t = threadIdx.x;
    float4 p = ((const float4*)(penta + (size_t)v * EDIM))[t];
    __shared__ float red[256];
    red[t] = p.x * p.x + p.y * p.y + p.z * p.z + p.w * p.w;
    __syncthreads();
    for (int off = 128; off > 0; off >>= 1) {
        if (t < off) red[t] += red[t + off];
        __syncthreads();
    }
    float inv = 1.0f / sqrtf(red[0]);
    float4 o = make_float4(p.x * inv, p.y * inv, p.z * inv, p.w * inv);
    ((float4*)(dirs + (size_t)v * EDIM))[t] = o;
}

// ---------------------------------------------------------------------------
// 3) gather token slice + gating MLP + scale -> smy (M x 512), M = B*N
//    one block per (b, j) token; 128 threads
// ---------------------------------------------------------------------------
__global__ __launch_bounds__(128) void gate_kernel(const float* __restrict__ tokens,
                                                   const int* __restrict__ idx,
                                                   const float* __restrict__ Wg1,
                                                   const float* __restrict__ bg1,
                                                   const float* __restrict__ Wg2,
                                                   const float* __restrict__ bg2,
                                                   const float* __restrict__ alpha,
                                                   float* __restrict__ smy, int Ntok) {
    int bn = blockIdx.x;
    int b = bn / Ntok;
    int j = bn - b * Ntok;
    int p = idx[j];
    int t = threadIdx.x;

    __shared__ float row[SLICE];
    const float* src = tokens + ((size_t)b * PTOK + p) * FULLD + SL_START;
    float4 v = ((const float4*)src)[t];
    ((float4*)row)[t] = v;
    __syncthreads();

    // h_t = dot(row, Wg1[t,:]) + bg1[t]
    const float4* w4 = (const float4*)(Wg1 + (size_t)t * SLICE);
    const float4* r4 = (const float4*)row;
    float acc = bg1[t];
#pragma unroll 8
    for (int k = 0; k < SLICE / 4; ++k) {
        float4 w = w4[k];
        float4 r = r4[k];
        acc += r.x * w.x + r.y * w.y + r.z * w.z + r.w * w.w;
    }
    // exact GELU: x * 0.5 * (1 + erf(x/sqrt(2)))
    float hg = 0.5f * acc * (1.0f + erff(acc * 0.70710678118654752f));

    __shared__ float red[128];
    red[t] = hg * Wg2[t];
    __syncthreads();
    for (int off = 64; off > 0; off >>= 1) {
        if (t < off) red[t] += red[t + off];
        __syncthreads();
    }
    float logit = red[0] + bg2[0];
    float gate = 1.0f / (1.0f + expf(-logit));
    float aw = 1.0f / (1.0f + expf(-alpha[0]));
    float s = gate * aw + (1.0f - aw);

    float4 o = make_float4(v.x * s, v.y * s, v.z * s, v.w * s);
    ((float4*)(smy + (size_t)bn * SLICE))[t] = o;
}

// ---------------------------------------------------------------------------
// 4) QKV GEMM: C[m,n] = sum_k A[m,k] * W[n,k];  A: M x 512, W: 1024 x 512
//    64x64 tile, BK=32, 256 threads, 4x4 per thread. grid.z picks Wq/Wk/Wv.
// ---------------------------------------------------------------------------
__global__ __launch_bounds__(256) void qkv_gemm(const float* __restrict__ A,
                                                const float* __restrict__ Wq,
                                                const float* __restrict__ Wk,
                                                const float* __restrict__ Wv,
                                                float* __restrict__ out, int M) {
    const float* W = (blockIdx.z == 0) ? Wq : ((blockIdx.z == 1) ? Wk : Wv);
    float* C = out + (size_t)blockIdx.z * M * EDIM;

    __shared__ float As[32][65];
    __shared__ float Bs[32][65];

    int tid = threadIdx.x;
    int bm = blockIdx.y * 64;
    int bn = blockIdx.x * 64;
    int tx = tid & 15, ty = tid >> 4;

    float acc[4][4] = {};

    for (int k0 = 0; k0 < SLICE; k0 += 32) {
#pragma unroll
        for (int i = 0; i < 2; ++i) {
            int pos = tid + i * 256;
            int row = pos >> 3;
            int c4 = (pos & 7) * 4;
            float4 va = make_float4(0.f, 0.f, 0.f, 0.f);
            if (bm + row < M)
                va = *(const float4*)(A + (size_t)(bm + row) * SLICE + k0 + c4);
            As[c4 + 0][row] = va.x;
            As[c4 + 1][row] = va.y;
            As[c4 + 2][row] = va.z;
            As[c4 + 3][row] = va.w;
            float4 vb = *(const float4*)(W + (size_t)(bn + row) * SLICE + k0 + c4);
            Bs[c4 + 0][row] = vb.x;
            Bs[c4 + 1][row] = vb.y;
            Bs[c4 + 2][row] = vb.z;
            Bs[c4 + 3][row] = vb.w;
        }
        __syncthreads();
#pragma unroll
        for (int kk = 0; kk < 32; ++kk) {
            float a[4], bb[4];
#pragma unroll
            for (int i = 0; i < 4; ++i) a[i] = As[kk][ty * 4 + i];
#pragma unroll
            for (int jj = 0; jj < 4; ++jj) bb[jj] = Bs[kk][tx * 4 + jj];
#pragma unroll
            for (int i = 0; i < 4; ++i)
#pragma unroll
                for (int jj = 0; jj < 4; ++jj) acc[i][jj] += a[i] * bb[jj];
        }
        __syncthreads();
    }

#pragma unroll
    for (int i = 0; i < 4; ++i) {
        int m = bm + ty * 4 + i;
        if (m < M) {
            float4 o = make_float4(acc[i][0], acc[i][1], acc[i][2], acc[i][3]);
            *(float4*)(C + (size_t)m * EDIM + bn + tx * 4) = o;
        }
    }
}

// ---------------------------------------------------------------------------
// 5) pentachoron projections: outp[(q*5+v)*M + m] = dot(QKV[q][m,:], dirs[v,:])
//    one block per (q, m); 256 threads
// ---------------------------------------------------------------------------
__global__ __launch_bounds__(256) void proj_kernel(const float* __restrict__ qkv,
                                                   const float* __restrict__ dirs,
                                                   float* __restrict__ outp, int M) {
    int bid = blockIdx.x;
    int q = bid / M;
    int m = bid - q * M;
    const float4* row = (const float4*)(qkv + ((size_t)q * M + m) * EDIM);
    int t = threadIdx.x;
    float4 v = row[t];
    float acc[5];
#pragma unroll
    for (int v5 = 0; v5 < 5; ++v5) {
        float4 d = ((const float4*)(dirs + (size_t)v5 * EDIM))[t];
        acc[v5] = v.x * d.x + v.y * d.y + v.z * d.z + v.w * d.w;
    }
    __shared__ float red[256];
#pragma unroll
    for (int v5 = 0; v5 < 5; ++v5) {
        red[t] = acc[v5];
        __syncthreads();
        for (int off = 128; off > 0; off >>= 1) {
            if (t < off) red[t] += red[t + off];
            __syncthreads();
        }
        if (t == 0) outp[(size_t)(q * 5 + v5) * M + m] = red[0];
        __syncthreads();
    }
}

// ---------------------------------------------------------------------------
extern "C" void kernel_launch(void* const* d_in, const int* in_sizes, int n_in,
                              void* d_out, int out_size, void* d_ws, size_t ws_size,
                              hipStream_t stream) {
    const float* tokens = (const float*)d_in[0];
    const float* fp     = (const float*)d_in[1];
    const float* Wg1    = (const float*)d_in[2];
    const float* bg1    = (const float*)d_in[3];
    const float* Wg2    = (const float*)d_in[4];
    const float* bg2    = (const float*)d_in[5];
    const float* alpha  = (const float*)d_in[6];
    const float* Wq     = (const float*)d_in[7];
    const float* Wk     = (const float*)d_in[8];
    const float* Wv     = (const float*)d_in[9];
    const float* penta  = (const float*)d_in[10];
    float* out = (float*)d_out;

    // out_size = N * (3*4*1024 + 3*5*4) = 12348 * N
    int Ntok = out_size / 12348;
    int M = BDIM * Ntok;

    int*   idx  = (int*)d_ws;
    float* smy  = (float*)d_ws + 4096;
    float* dirs = smy + (size_t)M * SLICE;

    scan_kernel<<<1, 1024, 0, stream>>>(fp, idx);
    dirs_kernel<<<5, 256, 0, stream>>>(penta, dirs);
    gate_kernel<<<M, 128, 0, stream>>>(tokens, idx, Wg1, bg1, Wg2, bg2, alpha, smy, Ntok);

    dim3 gg(EDIM / 64, (M + 63) / 64, 3);
    qkv_gemm<<<gg, 256, 0, stream>>>(smy, Wq, Wk, Wv, out, M);

    proj_kernel<<<3 * M, 256, 0, stream>>>(out, dirs, out + (size_t)3 * M * EDIM, M);
}

// Round 2
// 484.667 us; speedup vs baseline: 1.4496x; 1.4496x over previous
//
#include <hip/hip_runtime.h>
#include <hip/hip_bf16.h>
#include <math.h>

// Problem constants (from reference)
#define PTOK 4096      // P
#define BDIM 4         // B
#define FULLD 4096     // FULL
#define SLICE 512
#define SL_START 1024
#define EDIM 1024
#define FP_MIN_C 0.1875f
#define FP_MAX_C 0.4375f

typedef __attribute__((ext_vector_type(8))) short bf16x8;
typedef __attribute__((ext_vector_type(4))) float f32x4;

// round-to-nearest-even f32 -> bf16 bits
__device__ __forceinline__ unsigned short f2bf(float f) {
    unsigned int u = __float_as_uint(f);
    unsigned int r = (u + 0x7fffu + ((u >> 16) & 1u)) >> 16;
    return (unsigned short)r;
}

__device__ __forceinline__ void gl2lds16(const void* g, void* l) {
    __builtin_amdgcn_global_load_lds(
        (const __attribute__((address_space(1))) unsigned int*)g,
        (__attribute__((address_space(3))) unsigned int*)(unsigned long long)(uintptr_t)l,
        16, 0, 0);
}

// ---------------------------------------------------------------------------
// 1) mask + prefix-scan compaction of fingerprints -> idx[N]
// ---------------------------------------------------------------------------
__global__ __launch_bounds__(1024) void scan_kernel(const float* __restrict__ fp,
                                                    int* __restrict__ idx) {
    __shared__ int cnt[1024];
    int t = threadIdx.x;
    int m[4];
    int c = 0;
#pragma unroll
    for (int i = 0; i < 4; ++i) {
        float f = fp[t * 4 + i];
        m[i] = (f >= FP_MIN_C && f < FP_MAX_C) ? 1 : 0;
        c += m[i];
    }
    cnt[t] = c;
    __syncthreads();
    for (int off = 1; off < 1024; off <<= 1) {
        int add = (t >= off) ? cnt[t - off] : 0;
        __syncthreads();
        cnt[t] += add;
        __syncthreads();
    }
    int pos = cnt[t] - c;  // exclusive prefix
#pragma unroll
    for (int i = 0; i < 4; ++i) {
        if (m[i]) idx[pos++] = t * 4 + i;
    }
}

// ---------------------------------------------------------------------------
// 2) normalize pentachoron -> dirs (5 x 1024)
// ---------------------------------------------------------------------------
__global__ __launch_bounds__(256) void dirs_kernel(const float* __restrict__ penta,
                                                   float* __restrict__ dirs) {
    int v = blockIdx.x, t = threadIdx.x;
    float4 p = ((const float4*)(penta + (size_t)v * EDIM))[t];
    __shared__ float red[256];
    red[t] = p.x * p.x + p.y * p.y + p.z * p.z + p.w * p.w;
    __syncthreads();
    for (int off = 128; off > 0; off >>= 1) {
        if (t < off) red[t] += red[t + off];
        __syncthreads();
    }
    float inv = 1.0f / sqrtf(red[0]);
    float4 o = make_float4(p.x * inv, p.y * inv, p.z * inv, p.w * inv);
    ((float4*)(dirs + (size_t)v * EDIM))[t] = o;
}

// ---------------------------------------------------------------------------
// 3) convert one fp32 weight matrix (1024x512) to bf16; blockIdx.y picks W
// ---------------------------------------------------------------------------
__global__ __launch_bounds__(256) void wcvt_kernel(const float* __restrict__ Wq,
                                                   const float* __restrict__ Wk,
                                                   const float* __restrict__ Wv,
                                                   unsigned short* __restrict__ Wb) {
    const float* src = (blockIdx.y == 0) ? Wq : ((blockIdx.y == 1) ? Wk : Wv);
    unsigned short* dst = Wb + (size_t)blockIdx.y * EDIM * SLICE;
    int i = blockIdx.x * 256 + threadIdx.x;  // float4 index, 131072 total
    float4 v = ((const float4*)src)[i];
    ushort4 o;
    o.x = f2bf(v.x); o.y = f2bf(v.y); o.z = f2bf(v.z); o.w = f2bf(v.w);
    ((ushort4*)dst)[i] = o;
}

// ---------------------------------------------------------------------------
// 4) gather token slice + gating MLP + scale -> Ag (M x 512, bf16)
// ---------------------------------------------------------------------------
__global__ __launch_bounds__(128) void gate_kernel(const float* __restrict__ tokens,
                                                   const int* __restrict__ idx,
                                                   const float* __restrict__ Wg1,
                                                   const float* __restrict__ bg1,
                                                   const float* __restrict__ Wg2,
                                                   const float* __restrict__ bg2,
                                                   const float* __restrict__ alpha,
                                                   unsigned short* __restrict__ Ag,
                                                   int Ntok) {
    int bn = blockIdx.x;
    int b = bn / Ntok;
    int j = bn - b * Ntok;
    int p = idx[j];
    int t = threadIdx.x;

    __shared__ float row[SLICE];
    const float* src = tokens + ((size_t)b * PTOK + p) * FULLD + SL_START;
    float4 v = ((const float4*)src)[t];
    ((float4*)row)[t] = v;
    __syncthreads();

    const float4* w4 = (const float4*)(Wg1 + (size_t)t * SLICE);
    const float4* r4 = (const float4*)row;
    float acc = bg1[t];
#pragma unroll 8
    for (int k = 0; k < SLICE / 4; ++k) {
        float4 w = w4[k];
        float4 r = r4[k];
        acc += r.x * w.x + r.y * w.y + r.z * w.z + r.w * w.w;
    }
    float hg = 0.5f * acc * (1.0f + erff(acc * 0.70710678118654752f));

    __shared__ float red[128];
    red[t] = hg * Wg2[t];
    __syncthreads();
    for (int off = 64; off > 0; off >>= 1) {
        if (t < off) red[t] += red[t + off];
        __syncthreads();
    }
    float logit = red[0] + bg2[0];
    float gate = 1.0f / (1.0f + expf(-logit));
    float aw = 1.0f / (1.0f + expf(-alpha[0]));
    float s = gate * aw + (1.0f - aw);

    ushort4 o;
    o.x = f2bf(v.x * s); o.y = f2bf(v.y * s);
    o.z = f2bf(v.z * s); o.w = f2bf(v.w * s);
    ((ushort4*)(Ag + (size_t)bn * SLICE))[t] = o;
}

// ---------------------------------------------------------------------------
// 5) MFMA bf16 GEMM: C[m,n] = sum_k A[m,k] * W[n,k]
//    A: M x 512 bf16, W: 1024 x 512 bf16 (z picks Wq/Wk/Wv slice of Wb)
//    128x128 tile, BK=32, 256 threads = 4 waves (2x2), 16x16x32 MFMA 4x4/wave
// ---------------------------------------------------------------------------
__global__ __launch_bounds__(256) void qkv_mfma(const unsigned short* __restrict__ Ag,
                                                const unsigned short* __restrict__ Wb,
                                                float* __restrict__ out, int M) {
    __shared__ short As[128 * 32];
    __shared__ short Bs[128 * 32];

    const unsigned short* W = Wb + (size_t)blockIdx.z * EDIM * SLICE;
    float* C = out + (size_t)blockIdx.z * M * EDIM;

    int tid = threadIdx.x;
    int bm = blockIdx.y * 128;
    int bn = blockIdx.x * 128;
    int l = tid & 63;
    int w = tid >> 6;
    int wr = w >> 1, wc = w & 1;  // 2x2 wave grid
    int lane16 = l & 15, kq = l >> 4;

    // staging coords: row = r*64 + tid/4, col8 = (tid&3)*8
    int srow = tid >> 2;
    int scol = (tid & 3) * 8;

    f32x4 acc[4][4] = {};

    for (int k0 = 0; k0 < SLICE; k0 += 32) {
#pragma unroll
        for (int r = 0; r < 2; ++r) {
            int arow = bm + r * 64 + srow;
            if (arow >= M) arow = M - 1;  // clamp (stores are guarded)
            gl2lds16(Ag + (size_t)arow * SLICE + k0 + scol,
                     As + (r * 64 + srow) * 32 + scol);
            int brow = bn + r * 64 + srow;
            gl2lds16(W + (size_t)brow * SLICE + k0 + scol,
                     Bs + (r * 64 + srow) * 32 + scol);
        }
        __syncthreads();

        bf16x8 a[4], b[4];
#pragma unroll
        for (int i = 0; i < 4; ++i)
            a[i] = *(const bf16x8*)(As + (wr * 64 + i * 16 + lane16) * 32 + kq * 8);
#pragma unroll
        for (int j = 0; j < 4; ++j)
            b[j] = *(const bf16x8*)(Bs + (wc * 64 + j * 16 + lane16) * 32 + kq * 8);
#pragma unroll
        for (int i = 0; i < 4; ++i)
#pragma unroll
            for (int j = 0; j < 4; ++j)
                acc[i][j] = __builtin_amdgcn_mfma_f32_16x16x32_bf16(a[i], b[j], acc[i][j], 0, 0, 0);
        __syncthreads();
    }

    // D mapping: row m = (l>>4)*4 + reg, col n = l&15
#pragma unroll
    for (int i = 0; i < 4; ++i) {
        int m0 = bm + wr * 64 + i * 16 + kq * 4;
#pragma unroll
        for (int j = 0; j < 4; ++j) {
            int n = bn + wc * 64 + j * 16 + lane16;
            f32x4 v = acc[i][j];
#pragma unroll
            for (int r = 0; r < 4; ++r) {
                int m = m0 + r;
                if (m < M) C[(size_t)m * EDIM + n] = v[r];
            }
        }
    }
}

// ---------------------------------------------------------------------------
// 6) pentachoron projections, wave-per-row with shuffle reduce
//    outp[(q*5+v)*M + m] = dot(QKV[q][m,:], dirs[v,:])
// ---------------------------------------------------------------------------
__global__ __launch_bounds__(256) void proj_kernel(const float* __restrict__ qkv,
                                                   const float* __restrict__ dirs,
                                                   float* __restrict__ outp, int M) {
    __shared__ float dsh[5 * EDIM];
    int t = threadIdx.x;
#pragma unroll
    for (int i = 0; i < 5; ++i) {
        ((float4*)dsh)[i * 256 + t] = ((const float4*)dirs)[i * 256 + t];
    }
    __syncthreads();

    int gw = blockIdx.x * 4 + (t >> 6);  // global wave id = row id
    if (gw >= 3 * M) return;
    int l = t & 63;
    int q = gw / M;
    int m = gw - q * M;

    const float4* row = (const float4*)(qkv + ((size_t)q * M + m) * EDIM);
    float acc[5] = {0.f, 0.f, 0.f, 0.f, 0.f};
#pragma unroll
    for (int it = 0; it < 4; ++it) {
        int c4 = it * 64 + l;  // float4 index
        float4 v = row[c4];
#pragma unroll
        for (int v5 = 0; v5 < 5; ++v5) {
            float4 d = ((const float4*)dsh)[v5 * 256 + c4];
            acc[v5] += v.x * d.x + v.y * d.y + v.z * d.z + v.w * d.w;
        }
    }
#pragma unroll
    for (int v5 = 0; v5 < 5; ++v5) {
        float a = acc[v5];
        for (int off = 32; off > 0; off >>= 1) a += __shfl_down(a, off, 64);
        if (l == 0) outp[(size_t)(q * 5 + v5) * M + m] = a;
    }
}

// ---------------------------------------------------------------------------
extern "C" void kernel_launch(void* const* d_in, const int* in_sizes, int n_in,
                              void* d_out, int out_size, void* d_ws, size_t ws_size,
                              hipStream_t stream) {
    const float* tokens = (const float*)d_in[0];
    const float* fp     = (const float*)d_in[1];
    const float* Wg1    = (const float*)d_in[2];
    const float* bg1    = (const float*)d_in[3];
    const float* Wg2    = (const float*)d_in[4];
    const float* bg2    = (const float*)d_in[5];
    const float* alpha  = (const float*)d_in[6];
    const float* Wq     = (const float*)d_in[7];
    const float* Wk     = (const float*)d_in[8];
    const float* Wv     = (const float*)d_in[9];
    const float* penta  = (const float*)d_in[10];
    float* out = (float*)d_out;

    int Ntok = out_size / 12348;   // N tokens in window
    int M = BDIM * Ntok;

    // workspace layout (16B aligned)
    char* ws = (char*)d_ws;
    int*            idx  = (int*)ws;                         // 16 KB
    unsigned short* Ag   = (unsigned short*)(ws + (32 << 10));        // M*512*2 <= ~4.5MB
    unsigned short* Wb   = (unsigned short*)(ws + (8 << 20));         // 3MB
    float*          dirs = (float*)(ws + (12 << 20));                 // 20KB

    scan_kernel<<<1, 1024, 0, stream>>>(fp, idx);
    dirs_kernel<<<5, 256, 0, stream>>>(penta, dirs);
    wcvt_kernel<<<dim3(512, 3), 256, 0, stream>>>(Wq, Wk, Wv, Wb);
    gate_kernel<<<M, 128, 0, stream>>>(tokens, idx, Wg1, bg1, Wg2, bg2, alpha, Ag, Ntok);

    dim3 gg(EDIM / 128, (M + 127) / 128, 3);
    qkv_mfma<<<gg, 256, 0, stream>>>(Ag, Wb, out, M);

    proj_kernel<<<(3 * M + 3) / 4, 256, 0, stream>>>(out, dirs, out + (size_t)3 * M * EDIM, M);
}

// Round 3
// 387.335 us; speedup vs baseline: 1.8139x; 1.2513x over previous
//
#include <hip/hip_runtime.h>
#include <hip/hip_bf16.h>
#include <math.h>

// Problem constants (from reference)
#define PTOK 4096      // P
#define BDIM 4         // B
#define FULLD 4096     // FULL
#define SLICE 512
#define SL_START 1024
#define EDIM 1024
#define FP_MIN_C 0.1875f
#define FP_MAX_C 0.4375f

typedef __attribute__((ext_vector_type(8))) short bf16x8;
typedef __attribute__((ext_vector_type(4))) float f32x4;

// round-to-nearest-even f32 -> bf16 bits
__device__ __forceinline__ unsigned short f2bf(float f) {
    unsigned int u = __float_as_uint(f);
    unsigned int r = (u + 0x7fffu + ((u >> 16) & 1u)) >> 16;
    return (unsigned short)r;
}

__device__ __forceinline__ void gl2lds16(const void* g, void* l) {
    __builtin_amdgcn_global_load_lds(
        (const __attribute__((address_space(1))) unsigned int*)g,
        (__attribute__((address_space(3))) unsigned int*)(unsigned long long)(uintptr_t)l,
        16, 0, 0);
}

// ---------------------------------------------------------------------------
// 1) fused prep: block 0 = fingerprint scan; blocks 1..5 = dirs normalize;
//    blocks 6..389 = weight fp32->bf16 convert
// ---------------------------------------------------------------------------
__global__ __launch_bounds__(1024) void prep_kernel(const float* __restrict__ fp,
                                                    int* __restrict__ idx,
                                                    const float* __restrict__ penta,
                                                    float* __restrict__ dirs,
                                                    const float* __restrict__ Wq,
                                                    const float* __restrict__ Wk,
                                                    const float* __restrict__ Wv,
                                                    unsigned short* __restrict__ Wb) {
    int blk = blockIdx.x;
    int t = threadIdx.x;
    if (blk == 0) {
        // shuffle-based scan over 4096 fingerprints (4/thread)
        int m[4];
        int c = 0;
#pragma unroll
        for (int i = 0; i < 4; ++i) {
            float f = fp[t * 4 + i];
            m[i] = (f >= FP_MIN_C && f < FP_MAX_C) ? 1 : 0;
            c += m[i];
        }
        int lane = t & 63, wv = t >> 6;
        int inc = c;
#pragma unroll
        for (int off = 1; off < 64; off <<= 1) {
            int n = __shfl_up(inc, off, 64);
            if (lane >= off) inc += n;
        }
        __shared__ int wsum[16];
        if (lane == 63) wsum[wv] = inc;
        __syncthreads();
        if (t < 16) {
            int v = wsum[t];
            int in2 = v;
#pragma unroll
            for (int off = 1; off < 16; off <<= 1) {
                int n = __shfl_up(in2, off, 16);
                if (t >= off) in2 += n;
            }
            wsum[t] = in2 - v;  // exclusive wave base
        }
        __syncthreads();
        int pos = wsum[wv] + inc - c;
#pragma unroll
        for (int i = 0; i < 4; ++i) {
            if (m[i]) idx[pos++] = t * 4 + i;
        }
    } else if (blk <= 5) {
        int v = blk - 1;
        float4 p = make_float4(0.f, 0.f, 0.f, 0.f);
        float ss = 0.f;
        if (t < 256) {
            p = ((const float4*)(penta + (size_t)v * EDIM))[t];
            ss = p.x * p.x + p.y * p.y + p.z * p.z + p.w * p.w;
        }
        for (int off = 32; off > 0; off >>= 1) ss += __shfl_down(ss, off, 64);
        __shared__ float dsum[16];
        if ((t & 63) == 0) dsum[t >> 6] = ss;
        __syncthreads();
        if (t < 256) {
            float tot = dsum[0] + dsum[1] + dsum[2] + dsum[3];
            float inv = 1.0f / sqrtf(tot);
            float4 o = make_float4(p.x * inv, p.y * inv, p.z * inv, p.w * inv);
            ((float4*)(dirs + (size_t)v * EDIM))[t] = o;
        }
    } else {
        int i = (blk - 6) * 1024 + t;  // float4 index over 3*131072
        int mat = i >> 17;
        int rem = i & 131071;
        const float* src = (mat == 0) ? Wq : ((mat == 1) ? Wk : Wv);
        float4 v = ((const float4*)src)[rem];
        ushort4 o;
        o.x = f2bf(v.x); o.y = f2bf(v.y); o.z = f2bf(v.z); o.w = f2bf(v.w);
        ((ushort4*)(Wb + (size_t)mat * EDIM * SLICE))[rem] = o;
    }
}

// ---------------------------------------------------------------------------
// 2) gather + gating MLP + scale -> Ag (M x 512, bf16); 8 tokens per block
// ---------------------------------------------------------------------------
#define GT 8
__global__ __launch_bounds__(256) void gate_kernel(const float* __restrict__ tokens,
                                                   const int* __restrict__ idx,
                                                   const float* __restrict__ Wg1,
                                                   const float* __restrict__ bg1,
                                                   const float* __restrict__ Wg2,
                                                   const float* __restrict__ bg2,
                                                   const float* __restrict__ alpha,
                                                   unsigned short* __restrict__ Ag,
                                                   int Ntok, int M) {
    __shared__ float rows[GT][SLICE];   // 16 KB
    __shared__ float hred[GT][128];     // 4 KB
    __shared__ float ssc[GT];

    int tid = threadIdx.x;
    int tok0 = blockIdx.x * GT;

    // stage 8 token rows (coalesced within each half-row)
#pragma unroll
    for (int i = 0; i < 4; ++i) {
        int flat = i * 256 + tid;           // float4 slot
        int tk = flat >> 7, c4 = flat & 127;
        int g = tok0 + tk;
        if (g >= M) g = M - 1;
        int b = g / Ntok;
        int j = g - b * Ntok;
        int p = idx[j];
        const float4* src = (const float4*)(tokens + ((size_t)b * PTOK + p) * FULLD + SL_START);
        ((float4*)rows[tk])[c4] = src[c4];
    }
    __syncthreads();

    int hidx = tid & 127;
    int grp = tid >> 7;  // tokens grp*4 .. grp*4+3
    const float4* w4 = (const float4*)(Wg1 + (size_t)hidx * SLICE);
    float bias = bg1[hidx];
    float acc[4] = {bias, bias, bias, bias};
#pragma unroll 4
    for (int k = 0; k < SLICE / 4; ++k) {
        float4 w = w4[k];
#pragma unroll
        for (int t8 = 0; t8 < 4; ++t8) {
            float4 r = ((const float4*)rows[grp * 4 + t8])[k];
            acc[t8] += r.x * w.x + r.y * w.y + r.z * w.z + r.w * w.w;
        }
    }
    float wg2 = Wg2[hidx];
#pragma unroll
    for (int t8 = 0; t8 < 4; ++t8) {
        float a = acc[t8];
        float hg = 0.5f * a * (1.0f + erff(a * 0.70710678118654752f));
        hred[grp * 4 + t8][hidx] = hg * wg2;
    }
    __syncthreads();

    int wv = tid >> 6, l = tid & 63;
    float aw = 1.0f / (1.0f + expf(-alpha[0]));
#pragma unroll
    for (int z = 0; z < 2; ++z) {
        int tk = wv * 2 + z;
        float v = hred[tk][l] + hred[tk][l + 64];
        for (int off = 32; off > 0; off >>= 1) v += __shfl_down(v, off, 64);
        if (l == 0) {
            float logit = v + bg2[0];
            float gate = 1.0f / (1.0f + expf(-logit));
            ssc[tk] = gate * aw + (1.0f - aw);
        }
    }
    __syncthreads();

#pragma unroll
    for (int i = 0; i < 4; ++i) {
        int flat = i * 256 + tid;
        int tk = flat >> 7, c4 = flat & 127;
        int g = tok0 + tk;
        if (g < M) {
            float4 r = ((const float4*)rows[tk])[c4];
            float s = ssc[tk];
            ushort4 o;
            o.x = f2bf(r.x * s); o.y = f2bf(r.y * s);
            o.z = f2bf(r.z * s); o.w = f2bf(r.w * s);
            ((ushort4*)(Ag + (size_t)g * SLICE))[c4] = o;
        }
    }
}

// ---------------------------------------------------------------------------
// 3) MFMA bf16 GEMM: C[m,n] = sum_k A[m,k] * W[n,k]
//    128x128 tile, BK=64 as two 32-col panels (keeps global_load_lds lane
//    contiguity AND conflict-free 32-col ds_read layout), 16 barriers total.
// ---------------------------------------------------------------------------
__global__ __launch_bounds__(256) void qkv_mfma(const unsigned short* __restrict__ Ag,
                                                const unsigned short* __restrict__ Wb,
                                                float* __restrict__ out, int M) {
    __shared__ short As[2][128 * 32];
    __shared__ short Bs[2][128 * 32];

    const unsigned short* W = Wb + (size_t)blockIdx.z * EDIM * SLICE;
    float* C = out + (size_t)blockIdx.z * M * EDIM;

    int tid = threadIdx.x;
    int bm = blockIdx.y * 128;
    int bn = blockIdx.x * 128;
    int l = tid & 63;
    int w = tid >> 6;
    int wr = w >> 1, wc = w & 1;  // 2x2 wave grid
    int lane16 = l & 15, kq = l >> 4;

    int srow = tid >> 2;
    int scol = (tid & 3) * 8;

    f32x4 acc[4][4] = {};

    for (int k0 = 0; k0 < SLICE; k0 += 64) {
#pragma unroll
        for (int p = 0; p < 2; ++p) {
#pragma unroll
            for (int r = 0; r < 2; ++r) {
                int arow = bm + r * 64 + srow;
                if (arow >= M) arow = M - 1;  // clamp (stores are guarded)
                gl2lds16(Ag + (size_t)arow * SLICE + k0 + p * 32 + scol,
                         &As[p][(r * 64 + srow) * 32 + scol]);
                int brow = bn + r * 64 + srow;
                gl2lds16(W + (size_t)brow * SLICE + k0 + p * 32 + scol,
                         &Bs[p][(r * 64 + srow) * 32 + scol]);
            }
        }
        __syncthreads();

#pragma unroll
        for (int p = 0; p < 2; ++p) {
            bf16x8 a[4], b[4];
#pragma unroll
            for (int i = 0; i < 4; ++i)
                a[i] = *(const bf16x8*)&As[p][(wr * 64 + i * 16 + lane16) * 32 + kq * 8];
#pragma unroll
            for (int j = 0; j < 4; ++j)
                b[j] = *(const bf16x8*)&Bs[p][(wc * 64 + j * 16 + lane16) * 32 + kq * 8];
#pragma unroll
            for (int i = 0; i < 4; ++i)
#pragma unroll
                for (int j = 0; j < 4; ++j)
                    acc[i][j] = __builtin_amdgcn_mfma_f32_16x16x32_bf16(a[i], b[j], acc[i][j], 0, 0, 0);
        }
        __syncthreads();
    }

    // D mapping: row m = (l>>4)*4 + reg, col n = l&15
#pragma unroll
    for (int i = 0; i < 4; ++i) {
        int m0 = bm + wr * 64 + i * 16 + kq * 4;
#pragma unroll
        for (int j = 0; j < 4; ++j) {
            int n = bn + wc * 64 + j * 16 + lane16;
            f32x4 v = acc[i][j];
#pragma unroll
            for (int r = 0; r < 4; ++r) {
                int m = m0 + r;
                if (m < M) C[(size_t)m * EDIM + n] = v[r];
            }
        }
    }
}

// ---------------------------------------------------------------------------
// 4) pentachoron projections, wave-per-row with shuffle reduce
// ---------------------------------------------------------------------------
__global__ __launch_bounds__(256) void proj_kernel(const float* __restrict__ qkv,
                                                   const float* __restrict__ dirs,
                                                   float* __restrict__ outp, int M) {
    __shared__ float dsh[5 * EDIM];
    int t = threadIdx.x;
#pragma unroll
    for (int i = 0; i < 5; ++i) {
        ((float4*)dsh)[i * 256 + t] = ((const float4*)dirs)[i * 256 + t];
    }
    __syncthreads();

    int gw = blockIdx.x * 4 + (t >> 6);
    if (gw >= 3 * M) return;
    int l = t & 63;
    int q = gw / M;
    int m = gw - q * M;

    const float4* row = (const float4*)(qkv + ((size_t)q * M + m) * EDIM);
    float acc[5] = {0.f, 0.f, 0.f, 0.f, 0.f};
#pragma unroll
    for (int it = 0; it < 4; ++it) {
        int c4 = it * 64 + l;
        float4 v = row[c4];
#pragma unroll
        for (int v5 = 0; v5 < 5; ++v5) {
            float4 d = ((const float4*)dsh)[v5 * 256 + c4];
            acc[v5] += v.x * d.x + v.y * d.y + v.z * d.z + v.w * d.w;
        }
    }
#pragma unroll
    for (int v5 = 0; v5 < 5; ++v5) {
        float a = acc[v5];
        for (int off = 32; off > 0; off >>= 1) a += __shfl_down(a, off, 64);
        if (l == 0) outp[(size_t)(q * 5 + v5) * M + m] = a;
    }
}

// ---------------------------------------------------------------------------
extern "C" void kernel_launch(void* const* d_in, const int* in_sizes, int n_in,
                              void* d_out, int out_size, void* d_ws, size_t ws_size,
                              hipStream_t stream) {
    const float* tokens = (const float*)d_in[0];
    const float* fp     = (const float*)d_in[1];
    const float* Wg1    = (const float*)d_in[2];
    const float* bg1    = (const float*)d_in[3];
    const float* Wg2    = (const float*)d_in[4];
    const float* bg2    = (const float*)d_in[5];
    const float* alpha  = (const float*)d_in[6];
    const float* Wq     = (const float*)d_in[7];
    const float* Wk     = (const float*)d_in[8];
    const float* Wv     = (const float*)d_in[9];
    const float* penta  = (const float*)d_in[10];
    float* out = (float*)d_out;

    int Ntok = out_size / 12348;
    int M = BDIM * Ntok;

    char* ws = (char*)d_ws;
    int*            idx  = (int*)ws;
    unsigned short* Ag   = (unsigned short*)(ws + (32 << 10));
    unsigned short* Wb   = (unsigned short*)(ws + (8 << 20));
    float*          dirs = (float*)(ws + (12 << 20));

    prep_kernel<<<390, 1024, 0, stream>>>(fp, idx, penta, dirs, Wq, Wk, Wv, Wb);
    gate_kernel<<<(M + GT - 1) / GT, 256, 0, stream>>>(tokens, idx, Wg1, bg1, Wg2, bg2,
                                                       alpha, Ag, Ntok, M);

    dim3 gg(EDIM / 128, (M + 127) / 128, 3);
    qkv_mfma<<<gg, 256, 0, stream>>>(Ag, Wb, out, M);

    proj_kernel<<<(3 * M + 3) / 4, 256, 0, stream>>>(out, dirs, out + (size_t)3 * M * EDIM, M);
}